// Round 21
// baseline (1035.504 us; speedup 1.0000x reference)
//

#include <hip/hip_runtime.h>
#include <hip/hip_bf16.h>
#include <hip/hip_cooperative_groups.h>

// ROUND 21 (round 20: 884.4 us, absmax 0.0; sinkhorn train ~700 us across
// 201 launches incl. ~1.3 us/launch overhead):
//  - Persistent cooperative sinkhorn: ONE hipLaunchCooperativeKernel, 512
//    blocks (<=2/CU worst case), grid.sync() between half-iterations,
//    device-side early exit, finalOnly tail folded in.
//  - XCD affinity preserved (tile stride 512 == 0 mod 8).

#define NN 4096
#define LDA 4104          /* fp16 row stride for S (4097 padded to x8) */
#define DD 512
#define NCNUM 409         /* int(0.1*4096) */
#define REGc 0.03f
#define INVREG (1.0f/0.03f)
#define GAM 0.8f
#define THRESHc 1e-4f
#define LOGN 8.3177661667193433f   /* ln(4096) */
#define LOGM 8.3180102775477533f   /* ln(4097) */
#define NEGINF (-__builtin_inff())
#define SGRID 512                  /* persistent sinkhorn grid */

namespace cg = cooperative_groups;

typedef unsigned short u16;
typedef unsigned int u32;
typedef _Float16 f16;

struct alignas(16) Q  { u32 x, y, z, w; };
struct alignas(8)  Q2 { u32 x, y; };
struct alignas(16) F4 { float a, b, c, d; };
union H8 { Q q; f16 h[8]; };

typedef __attribute__((ext_vector_type(8))) short frag_ab;   /* 8 bf16 */
typedef __attribute__((ext_vector_type(4))) float frag_cd;   /* 4 f32  */

__device__ __forceinline__ float bf2f(u32 u) { return __uint_as_float(u << 16); }
__device__ __forceinline__ float bflo(u32 w) { return __uint_as_float(w << 16); }
__device__ __forceinline__ float bfhi(u32 w) { return __uint_as_float(w & 0xFFFF0000u); }
__device__ __forceinline__ u16 f2bf_rne(float f) {
  u32 b = __float_as_uint(f);
  b += 0x7FFFu + ((b >> 16) & 1u);
  return (u16)(b >> 16);
}
__device__ __forceinline__ u16 f2h_hw(float f) {
  union { f16 h; u16 u; } X; X.h = (f16)f; return X.u;
}
__device__ __forceinline__ float h2f_hw(u16 v) {
  union { u16 u; f16 h; } X; X.u = v; return (float)X.h;
}
__device__ __forceinline__ void unpack8(Q q, float* x) {
  H8 u; u.q = q;
  #pragma unroll
  for (int c = 0; c < 8; ++c) x[c] = (float)u.h[c];
}
__device__ __forceinline__ float gload(const float* p) {
  return __hip_atomic_load(p, __ATOMIC_RELAXED, __HIP_MEMORY_SCOPE_AGENT);
}
__device__ __forceinline__ void lse_merge(float& m, float& s, float om, float os) {
  float nm = fmaxf(m, om);
  if (nm == NEGINF) return;
  float acc = 0.f;
  if (s  > 0.f) acc += s  * __expf(m  - nm);
  if (os > 0.f) acc += os * __expf(om - nm);
  m = nm; s = acc;
}
__device__ __forceinline__ float blockReduce256(float v) {
  __shared__ float sh[4];
  #pragma unroll
  for (int off = 32; off >= 1; off >>= 1) v += __shfl_xor(v, off);
  int w = threadIdx.x >> 6;
  if ((threadIdx.x & 63) == 0) sh[w] = v;
  __syncthreads();
  float r = 0.f;
  if (threadIdx.x == 0) r = sh[0] + sh[1] + sh[2] + sh[3];
  __syncthreads();
  return r;
}

__global__ void ContrastiveLoss_83391085019222_kernel(float* out) {
  if (threadIdx.x == 0) { out[0] = 0.5f; out[1] = 0.5f; }
}
__global__ void diag_kernel(float* out, float a, float b) {
  if (threadIdx.x == 0) { out[0] = a; out[1] = b; }
}

/* ---- dtype autodetect: inputs are unit-normalized rows ---- */
__global__ void detect_kernel(const u16* img, float* misc) {
  const int lane = threadIdx.x;  /* 64 */
  float nb = 0.f, nf = 0.f;
  const float* fimg = (const float*)img;
  for (int c = lane * 8; c < lane * 8 + 8; ++c) {
    float xb = bf2f((u32)img[c]);
    nb += xb * xb;
    float xf = fimg[c];
    if (fabsf(xf) < 1e10f) nf += xf * xf; else nf += 1e10f;
  }
  #pragma unroll
  for (int off = 32; off >= 1; off >>= 1) { nb += __shfl_xor(nb, off); nf += __shfl_xor(nf, off); }
  if (lane == 0) {
    float db = fabsf(nb - 1.f);
    float df = fabsf(nf - 1.f);
    if (!(db == db)) db = 1e30f;
    if (!(df == df)) df = 1e30f;
    ((int*)misc)[10] = (df < db) ? 1 : 0;   /* 1 = float32 inputs */
  }
}

/* ---- convert img/txt to bf16 planes ---- */
__global__ void cvt_kernel(const u16* img, const u16* txt,
                           u16* Abf, u16* Bbf, const float* misc) {
  const int isF = ((const int*)misc)[10];
  const int t = blockIdx.x * 256 + threadIdx.x;
  const int base = t * 4;
  if (isF) {
    const float* fi = (const float*)img;
    const float* ft = (const float*)txt;
    ushort4 oa, ob;
    oa.x = f2bf_rne(fi[base+0]); oa.y = f2bf_rne(fi[base+1]);
    oa.z = f2bf_rne(fi[base+2]); oa.w = f2bf_rne(fi[base+3]);
    ob.x = f2bf_rne(ft[base+0]); ob.y = f2bf_rne(ft[base+1]);
    ob.z = f2bf_rne(ft[base+2]); ob.w = f2bf_rne(ft[base+3]);
    *(ushort4*)(Abf + base) = oa;
    *(ushort4*)(Bbf + base) = ob;
  } else {
    *(ushort4*)(Abf + base) = *(const ushort4*)(img + base);
    *(ushort4*)(Bbf + base) = *(const ushort4*)(txt + base);
  }
}

/* init: zero vecs(16400) + errs(256) + rsA0(4096) + csA0(4104), scale */
__global__ void init_kernel(const u16* ls, float* vecs, float* errs,
                            float* rsA0, float* csA0, float* misc) {
  int t = blockIdx.x * 256 + threadIdx.x;
  if (t < 16400) vecs[t] = 0.f;
  if (t < 256)  errs[t] = 0.f;
  if (t < 4096) rsA0[t] = 0.f;
  if (t < 4104) csA0[t] = 0.f;
  if (t == 0) {
    const int isF = ((const int*)misc)[10];
    float lsv = isF ? ((const float*)ls)[0] : bf2f((u32)ls[0]);
    misc[0] = __expf(lsv);               /* scale = exp(logit_scale) */
  }
}

/* ------- MFMA GEMM: S = Abf x Bbf^T -> fp16 + per-block min ------- */
__global__ __launch_bounds__(256) void gemm_mfma(const u16* Abf, const u16* Bbf,
                                                 u16* S, float* gmin) {
  __shared__ float red[256];
  const int tid = threadIdx.x;
  const int wave = tid >> 6, lane = tid & 63;
  const int wr = wave >> 1, wc = wave & 1;
  const int rb = (int)blockIdx.y * 128 + wr * 64;
  const int cb = (int)blockIdx.x * 128 + wc * 64;
  const int l15 = lane & 15, q = lane >> 4;

  frag_cd acc[4][4];
  #pragma unroll
  for (int i = 0; i < 4; ++i)
    #pragma unroll
    for (int j = 0; j < 4; ++j) acc[i][j] = (frag_cd){0.f, 0.f, 0.f, 0.f};

  for (int kt = 0; kt < DD; kt += 32) {
    frag_ab af[4], bfr[4];
    #pragma unroll
    for (int t = 0; t < 4; ++t) {
      af[t]  = *(const frag_ab*)(Abf + (size_t)(rb + t*16 + l15) * DD + kt + q*8);
      bfr[t] = *(const frag_ab*)(Bbf + (size_t)(cb + t*16 + l15) * DD + kt + q*8);
    }
    #pragma unroll
    for (int i = 0; i < 4; ++i)
      #pragma unroll
      for (int j = 0; j < 4; ++j)
        acc[i][j] = __builtin_amdgcn_mfma_f32_16x16x32_bf16(af[i], bfr[j], acc[i][j], 0, 0, 0);
  }

  float lmin = 1e30f;
  #pragma unroll
  for (int i = 0; i < 4; ++i) {
    #pragma unroll
    for (int j = 0; j < 4; ++j) {
      #pragma unroll
      for (int r = 0; r < 4; ++r) {
        const int row = rb + i*16 + q*4 + r;
        const int col = cb + j*16 + l15;
        u16 h = f2h_hw(acc[i][j][r]);
        lmin = fminf(lmin, h2f_hw(h));
        S[(size_t)row * LDA + col] = h;
      }
    }
  }
  red[tid] = lmin;
  __syncthreads();
  for (int sN = 128; sN >= 1; sN >>= 1) {
    if (tid < sN) red[tid] = fminf(red[tid], red[tid + sN]);
    __syncthreads();
  }
  if (tid == 0) gmin[blockIdx.y * 32 + blockIdx.x] = red[0];
}

/* ------- sims_no -> S col NN + loss_op partial ------- */
__global__ void colvec_kernel(const u16* img, const u16* txt, const u16* tno,
                              u16* S, float* colvals, float* opP, const float* misc) {
  __shared__ float shOp[4];
  const int isF = ((const int*)misc)[10];
  const int wv = threadIdx.x >> 6;
  const int row = (int)(blockIdx.x << 2) + wv;
  const int lane = threadIdx.x & 63;
  const size_t base = (size_t)row * DD + lane * 8;
  float xi[8], xt[8], xn[8];
  if (isF) {
    const float* fi = (const float*)img;
    const float* ft = (const float*)txt;
    const float* fn = (const float*)tno;
    #pragma unroll
    for (int c = 0; c < 8; ++c) { xi[c] = fi[base+c]; xt[c] = ft[base+c]; xn[c] = fn[base+c]; }
  } else {
    Q qi = *(const Q*)(img + base);
    Q qt = *(const Q*)(txt + base);
    Q qn = *(const Q*)(tno + base);
    xi[0]=bflo(qi.x); xi[1]=bfhi(qi.x); xi[2]=bflo(qi.y); xi[3]=bfhi(qi.y);
    xi[4]=bflo(qi.z); xi[5]=bfhi(qi.z); xi[6]=bflo(qi.w); xi[7]=bfhi(qi.w);
    xt[0]=bflo(qt.x); xt[1]=bfhi(qt.x); xt[2]=bflo(qt.y); xt[3]=bfhi(qt.y);
    xt[4]=bflo(qt.z); xt[5]=bfhi(qt.z); xt[6]=bflo(qt.w); xt[7]=bfhi(qt.w);
    xn[0]=bflo(qn.x); xn[1]=bfhi(qn.x); xn[2]=bflo(qn.y); xn[3]=bfhi(qn.y);
    xn[4]=bflo(qn.z); xn[5]=bfhi(qn.z); xn[6]=bflo(qn.w); xn[7]=bfhi(qn.w);
  }
  float sn = 0.f, cs = 0.f;
  #pragma unroll
  for (int c = 0; c < 8; ++c) { sn += xi[c]*xn[c]; cs += xt[c]*xn[c]; }
  #pragma unroll
  for (int off = 32; off >= 1; off >>= 1) { sn += __shfl_xor(sn, off); cs += __shfl_xor(cs, off); }
  if (lane == 0) {
    colvals[row] = sn;
    S[(size_t)row * LDA + NN] = f2h_hw(sn);
    shOp[wv] = fmaxf(cs + 0.2f, 0.f) + fmaxf(-0.7f - cs, 0.f);
  }
  __syncthreads();
  if (threadIdx.x == 0) opP[blockIdx.x] = shOp[0] + shOp[1] + shOp[2] + shOp[3];
}

__global__ void reduce_kernel(const float* gmin, const float* colvals,
                              const float* opP, float* misc) {
  __shared__ float smin[256];
  __shared__ float ssum[256];
  float mn = 1e30f, sm = 0.f;
  for (int i = threadIdx.x; i < 1024; i += 256) mn = fminf(mn, gmin[i]);
  for (int i = threadIdx.x; i < 4096; i += 256) mn = fminf(mn, h2f_hw(f2h_hw(colvals[i])));
  for (int i = threadIdx.x; i < 1024; i += 256) sm += opP[i];
  smin[threadIdx.x] = mn; ssum[threadIdx.x] = sm;
  __syncthreads();
  for (int sN = 128; sN >= 1; sN >>= 1) {
    if (threadIdx.x < sN) {
      smin[threadIdx.x] = fminf(smin[threadIdx.x], smin[threadIdx.x + sN]);
      ssum[threadIdx.x] += ssum[threadIdx.x + sN];
    }
    __syncthreads();
  }
  if (threadIdx.x == 0) {
    float maxC = 1.0f - smin[0];         /* max(1-S) = 1 - min(S) */
    float a = 1.0f / (maxC * REGc);
    misc[1] = a;
    misc[4] = ssum[0];
    misc[5] = __expf(-a);                /* ea */
  }
}

__global__ void preds_kernel(const u16* S, const float* misc, float* preds) {
  const int row = (int)(blockIdx.x << 2) + (int)(threadIdx.x >> 6);
  const int lane = threadIdx.x & 63;
  const float scale = misc[0];
  const u16* Sr = S + (size_t)row * LDA;
  float m = NEGINF, s = 0.f;
  for (int it = 0; it < 8; ++it) {
    const int j0 = (it << 9) + (lane << 3);
    float x[8];
    unpack8(*(const Q*)(Sr + j0), x);
    float lm = NEGINF;
    #pragma unroll
    for (int c = 0; c < 8; ++c) { x[c] *= scale; lm = fmaxf(lm, x[c]); }
    float lsum = 0.f;
    #pragma unroll
    for (int c = 0; c < 8; ++c) lsum += __expf(x[c] - lm);
    lse_merge(m, s, lm, lsum);
  }
  #pragma unroll
  for (int off = 32; off >= 1; off >>= 1) {
    float om = __shfl_xor(m, off), os = __shfl_xor(s, off);
    lse_merge(m, s, om, os);
  }
  if (lane == 0) {
    float sii = h2f_hw(Sr[row]);
    preds[row] = __expf(scale * sii - m) / s;
  }
}

/* ------- nc rank: one block per row ------- */
__global__ void rank_kernel(const float* preds, int* is_nc) {
  const int i = blockIdx.x;
  const float pv = preds[i];
  float cnt = 0.f;
  for (int k2 = threadIdx.x; k2 < NN; k2 += 256) {
    float pk = preds[k2];
    cnt += (pk < pv || (pk == pv && k2 < i)) ? 1.f : 0.f;
  }
  cnt = blockReduce256(cnt);
  if (threadIdx.x == 0) is_nc[i] = (cnt < (float)NCNUM) ? 1 : 0;
}

__device__ __forceinline__ bool unmasked(int j, int r, bool ncr) {
  return (j == NN) ? ncr : !((j == r) && ncr);
}

/* ------- one sinkhorn half-iteration phase (device) ------- */
__device__ __forceinline__ void sink_phase(
    const u16* S, const int* is_nc, float a, float ea,
    const float* prevRow, const float* prevCol,
    float* outRow, float* outCol,
    float* z1, float* z2, int nz1, int nz2,
    float* u, float* ut, float* vvec, float* vtvec,
    float* errs1, float* errs2,
    int k, int roleB, int finalOnly,
    int c1, int c2, int c1p, int c2p,
    float* shW1, float* shW2, float (*shAcc)[128], float* se)
{
  const int bid = blockIdx.x, tid = threadIdx.x;
  const int gRow = roleB ? c2 : c1;
  const int gCol = roleB ? c1 : c2;

  if (!finalOnly) {
    int tot = nz1 + nz2;
    for (int z = bid * 256 + tid; z < tot; z += SGRID * 256) {
      if (z < nz1) z1[z] = 0.f; else z2[z - nz1] = 0.f;
    }
  }

  for (int t = bid; t < 1056; t += SGRID) {
    const int rt = t & 31, ct = t >> 5;
    const int cbase = ct << 7, r0 = rt << 7;
    __syncthreads();
    float errd = 0.f;
    if (tid < 128) {
      const int i = r0 + tid;
      float w = 0.f;
      if (!roleB) {
        if (!finalOnly && !gCol) w = (k == 0) ? ea : ea / (4096.0f * prevRow[i]);
        if (ct == 0 && k >= 1 && !c2p) vtvec[i] = REGc * (-LOGN - __logf(prevRow[i]));
      } else {
        if (!gCol) {
          w = ea / (4096.0f * prevRow[i]);
          if (ct == 0) {
            float un = REGc * (-LOGN - __logf(prevRow[i]));
            errd = fabsf(un - u[i]);
            u[i] = un;
          }
        }
      }
      shW2[tid] = w;
    } else {
      const int j = cbase + (tid - 128);
      float w = 0.f;
      if (j <= NN) {
        if (!roleB) {
          if (!finalOnly && !gRow) w = (k == 0) ? ea : ea / (4097.0f * prevCol[j]);
          if (rt == 0 && k >= 1 && !c1p) vvec[j] = REGc * (-LOGM - __logf(prevCol[j]));
        } else {
          if (!gRow) {
            w = ea / (4097.0f * prevCol[j]);
            if (rt == 0) {
              float un = REGc * (-LOGM - __logf(prevCol[j]));
              errd = fabsf(un - ut[j]);
              ut[j] = un;
            }
          }
        }
      }
      shW1[tid - 128] = w;
    }
    __syncthreads();

    if (!finalOnly && !(gRow && gCol)) {
      const int tc = tid & 15, tr = tid >> 4;
      const int j0c = tc << 3;
      const int j0 = cbase + j0c;
      const bool anyv = (j0 <= NN);
      unsigned jval = 0;
      #pragma unroll
      for (int c = 0; c < 8; ++c) if (j0 + c <= NN) jval |= 1u << c;
      float W1l[8];
      #pragma unroll
      for (int c = 0; c < 8; ++c) W1l[c] = shW1[j0c + c];
      float cs[8];
      #pragma unroll
      for (int c = 0; c < 8; ++c) cs[c] = 0.f;
      for (int st = 0; st < 8; ++st) {
        const int rr = (st << 4) + tr;
        const int r = r0 + rr;
        float E[8];
        if (anyv) {
          float xv[8];
          unpack8(*(const Q*)(S + (size_t)r * LDA + j0), xv);
          const bool ncr = (is_nc[r] != 0);
          #pragma unroll
          for (int c = 0; c < 8; ++c) {
            E[c] = __expf(xv[c] * a);
            if (!((jval >> c & 1u) && unmasked(j0 + c, r, ncr))) E[c] = 0.f;
          }
        } else {
          #pragma unroll
          for (int c = 0; c < 8; ++c) E[c] = 0.f;
        }
        if (!gCol) {
          float Wr = shW2[rr];
          #pragma unroll
          for (int c = 0; c < 8; ++c) cs[c] = fmaf(E[c], Wr, cs[c]);
        }
        if (!gRow) {
          float rs = 0.f;
          #pragma unroll
          for (int c = 0; c < 8; ++c) rs = fmaf(E[c], W1l[c], rs);
          #pragma unroll
          for (int off = 8; off >= 1; off >>= 1) rs += __shfl_xor(rs, off);
          if (tc == 0) atomicAdd(&outRow[r], rs);
        }
      }
      if (!gCol) {
        #pragma unroll
        for (int c = 0; c < 8; ++c) shAcc[tr][j0c + c] = cs[c];
        __syncthreads();
        if (tid < 128) {
          float s = 0.f;
          #pragma unroll
          for (int g = 0; g < 16; ++g) s += shAcc[g][tid];
          const int j = cbase + tid;
          if (j <= NN) atomicAdd(&outCol[j], s);
        }
      }
    }

    if (roleB) {
      #pragma unroll
      for (int off = 32; off >= 1; off >>= 1) errd += __shfl_xor(errd, off);
      if ((tid & 63) == 0) se[tid >> 6] = errd;
      __syncthreads();
      if (tid == 0) {
        if (ct == 0) atomicAdd(&errs1[k], se[0] + se[1]);
        if (rt == 0) atomicAdd(&errs2[k], se[2] + se[3]);
      }
    }
  }
}

/* ------- persistent cooperative sinkhorn ------- */
__global__ __launch_bounds__(256) void sink_persist(
    const u16* S, const float* misc,
    float* errs1, float* errs2,
    float* u, float* ut, float* vvec, float* vtvec,
    float* rsA0, float* rsA1, float* csA0, float* csA1,
    float* rsB0, float* rsB1, float* csB0, float* csB1,
    const int* is_nc)
{
  cg::grid_group grid = cg::this_grid();
  __shared__ float shW1[128];
  __shared__ float shW2[128];
  __shared__ float shAcc[16][128];
  __shared__ float se[4];
  const float a = misc[1], ea = misc[5];
  float* rsA[2] = { rsA0, rsA1 };
  float* csA[2] = { csA0, csA1 };
  float* rsB[2] = { rsB0, rsB1 };
  float* csB[2] = { csB0, csB1 };

  for (int k = 0; k < 100; ++k) {
    const int p = k & 1, q = (k + 1) & 1;
    const int pm = (k > 0) ? ((k - 1) & 1) : 0;
    float e1a = (k >= 1) ? gload(errs1 + k - 1) : 1e9f;
    float e2a = (k >= 1) ? gload(errs2 + k - 1) : 1e9f;
    float e1b = (k >= 2) ? gload(errs1 + k - 2) : 1e9f;
    float e2b = (k >= 2) ? gload(errs2 + k - 2) : 1e9f;
    const int c1 = e1a < THRESHc, c2 = e2a < THRESHc;
    const int c1p = e1b < THRESHc, c2p = e2b < THRESHc;

    sink_phase(S, is_nc, a, ea, rsB[pm], csB[pm], rsA[p], csA[p],
               csB[p], rsB[p], 4104, 4096,
               u, ut, vvec, vtvec, errs1, errs2,
               k, 0, 0, c1, c2, c1p, c2p, shW1, shW2, shAcc, se);
    grid.sync();
    sink_phase(S, is_nc, a, ea, rsA[p], csA[p], rsB[p], csB[p],
               rsA[q], csA[q], 4096, 4104,
               u, ut, vvec, vtvec, errs1, errs2,
               k, 1, 0, c1, c2, c1p, c2p, shW1, shW2, shAcc, se);
    grid.sync();
    float f1 = gload(errs1 + k), f2 = gload(errs2 + k);
    if (f1 < THRESHc && f2 < THRESHc && e1a < THRESHc && e2a < THRESHc) break;
  }
  /* tail: finalOnly role A at k=100 (writes final vvec/vtvec if the
     corresponding sinkhorn never converged; gates via errs[98]). */
  {
    float e1b = gload(errs1 + 98), e2b = gload(errs2 + 98);
    const int c1p = e1b < THRESHc, c2p = e2b < THRESHc;
    sink_phase(S, is_nc, a, ea, rsB[1], csB[1], rsA[0], csA[0],
               csB[0], rsB[0], 4104, 4096,
               u, ut, vvec, vtvec, errs1, errs2,
               100, 0, 1, 1, 1, c1p, c2p, shW1, shW2, shAcc, se);
  }
}

/* ------- final pass 1 (128x128 tiles, grid (33,32)) ------- */
__global__ __launch_bounds__(256) void final_pass(const u16* S, const float* vvec,
                           const float* vtvec, const float* misc, const int* is_nc,
                           float* rowLm, float* rowLs, float* rowGs,
                           float* colLm, float* colLs, float* colGs) {
  const float a = misc[1], scale = misc[0];
  const int ct = blockIdx.x, rt = blockIdx.y;
  const int tid = threadIdx.x;
  const int tc = tid & 15, tr = tid >> 4;
  const int cbase = ct << 7, r0 = rt << 7;
  const int j0 = cbase + (tc << 3);
  const bool anyv = (j0 <= NN);
  float wc[8]; unsigned jval = 0;
  #pragma unroll
  for (int c = 0; c < 8; ++c) {
    int j = j0 + c;
    wc[c] = 0.f;
    if (j <= NN) { jval |= 1u << c; wc[c] = vvec[j] * INVREG; }
  }
  float cLm[8], cLs[8], cGs[8];
  #pragma unroll
  for (int c = 0; c < 8; ++c) { cLm[c] = NEGINF; cLs[c] = 0.f; cGs[c] = 0.f; }
  for (int st = 0; st < 8; ++st) {
    const int r = r0 + (st << 4) + tr;
    float xv[8], lg[8]; unsigned um = 0;
    #pragma unroll
    for (int c = 0; c < 8; ++c) { xv[c] = 0.f; lg[c] = 0.f; }
    if (anyv) {
      float raw[8];
      unpack8(*(const Q*)(S + (size_t)r * LDA + j0), raw);
      const bool ncr = (is_nc[r] != 0);
      const float vtr = vtvec[r] * INVREG;
      #pragma unroll
      for (int c = 0; c < 8; ++c) {
        if (!(jval >> c & 1u)) continue;
        xv[c] = raw[c] * a;
        lg[c] = scale * raw[c];
        cGs[c] += __expf(lg[c]);
        if (unmasked(j0 + c, r, ncr)) {
          um |= 1u << c;
          float e2 = xv[c] + vtr;
          float nm = fmaxf(cLm[c], e2);
          cLs[c] = cLs[c] * __expf(cLm[c] - nm) + __expf(e2 - nm);
          cLm[c] = nm;
        }
      }
    }
    float rsG = 0.f;
    if (anyv) {
      #pragma unroll
      for (int c = 0; c < 8; ++c) if (jval >> c & 1u) rsG += __expf(lg[c]);
    }
    #pragma unroll
    for (int off = 8; off >= 1; off >>= 1) rsG += __shfl_xor(rsG, off);
    float rmL = NEGINF;
    if (anyv) {
      #pragma unroll
      for (int c = 0; c < 8; ++c) if (um >> c & 1u) rmL = fmaxf(rmL, xv[c] + wc[c]);
    }
    #pragma unroll
    for (int off = 8; off >= 1; off >>= 1) rmL = fmaxf(rmL, __shfl_xor(rmL, off));
    float rsL = 0.f;
    if (anyv && rmL > NEGINF) {
      #pragma unroll
      for (int c = 0; c < 8; ++c) if (um >> c & 1u) rsL += __expf(xv[c] + wc[c] - rmL);
    }
    #pragma unroll
    for (int off = 8; off >= 1; off >>= 1) rsL += __shfl_xor(rsL, off);
    if (tc == 0) {
      rowGs[ct * NN + r] = rsG;
      rowLm[ct * NN + r] = rmL;
      rowLs[ct * NN + r] = rsL;
    }
  }
  __shared__ float shm[16][128];
  __shared__ float shs[16][128];
  #pragma unroll
  for (int c = 0; c < 8; ++c) { shm[tr][(tc << 3) + c] = cLm[c]; shs[tr][(tc << 3) + c] = cLs[c]; }
  __syncthreads();
  if (tid < 128) {
    float m = NEGINF, s = 0.f;
    #pragma unroll
    for (int g = 0; g < 16; ++g) lse_merge(m, s, shm[g][tid], shs[g][tid]);
    const int j = cbase + tid;
    if (j <= NN) { colLm[rt * LDA + j] = m; colLs[rt * LDA + j] = s; }
  }
  __syncthreads();
  #pragma unroll
  for (int c = 0; c < 8; ++c) shs[tr][(tc << 3) + c] = cGs[c];
  __syncthreads();
  if (tid < 128) {
    float s = 0.f;
    #pragma unroll
    for (int g = 0; g < 16; ++g) s += shs[g][tid];
    const int j = cbase + tid;
    if (j <= NN) colGs[rt * LDA + j] = s;
  }
}

__global__ void final_combine(const float* rowLm, const float* rowLs, const float* rowGs,
                              const float* colLm, const float* colLs, const float* colGs,
                              float* LSMrow, float* LBLm, float* LBLs,
                              float* LSMcol, float* LBTm, float* LBTs) {
  const int b = blockIdx.x;
  if (b < 16) {
    const int i = (b << 8) + threadIdx.x;
    float m = NEGINF, s = 0.f, sg = 0.f;
    for (int t = 0; t < 33; ++t) {
      lse_merge(m, s, rowLm[t * NN + i], rowLs[t * NN + i]);
      sg += rowGs[t * NN + i];
    }
    LBLm[i] = m; LBLs[i] = s;
    LSMrow[i] = __logf(sg);
  } else {
    const int j = ((b - 16) << 8) + threadIdx.x;
    if (j <= NN) {
      float m = NEGINF, s = 0.f, sg = 0.f;
      for (int t = 0; t < 32; ++t) {
        lse_merge(m, s, colLm[t * LDA + j], colLs[t * LDA + j]);
        sg += colGs[t * LDA + j];
      }
      LBTm[j] = m; LBTs[j] = s;
      LSMcol[j] = __logf(sg);
    }
  }
}

/* ------- final pass 2: KL sums (128x128 tiles, grid (33,32)) ------- */
__global__ __launch_bounds__(256) void loss_pass(const u16* S, const float* vvec,
                          const float* vtvec, const float* misc, const int* is_nc,
                          const float* LSMrow, const float* LBLm, const float* LBLs,
                          const float* LSMcol, const float* LBTm, const float* LBTs,
                          float* imgP, float* txtP) {
  const float a = misc[1], scale = misc[0];
  const int ct = blockIdx.x, rt = blockIdx.y;
  const int tid = threadIdx.x;
  const int tc = tid & 15, tr = tid >> 4;
  const int cbase = ct << 7, r0 = rt << 7;
  const int j0 = cbase + (tc << 3);
  const bool anyv = (j0 <= NN);
  float vcw[8], bm[8], bsi[8], cg2[8]; unsigned jval = 0;
  #pragma unroll
  for (int c = 0; c < 8; ++c) {
    int j = j0 + c;
    vcw[c] = 0.f; bm[c] = 0.f; bsi[c] = 0.f; cg2[c] = 0.f;
    if (j <= NN) {
      jval |= 1u << c;
      vcw[c] = vvec[j] * INVREG; bm[c] = LBTm[j]; bsi[c] = 1.f / LBTs[j]; cg2[c] = LSMcol[j];
    }
  }
  float sImg = 0.f, sTxt = 0.f;
  for (int st = 0; st < 8; ++st) {
    const int r = r0 + (st << 4) + tr;
    if (anyv) {
      float raw[8];
      unpack8(*(const Q*)(S + (size_t)r * LDA + j0), raw);
      const bool ncr = (is_nc[r] != 0);
      const float vtr = vtvec[r] * INVREG;
      const float rm = LBLm[r], rsi = 1.f / LBLs[r], rg = LSMrow[r];
      #pragma unroll
      for (int c = 0; c < 8; ++c) {
        if (!(jval >> c & 1u)) continue;
        const int j = j0 + c;
        float xv = raw[c] * a;
        float lgt = scale * raw[c];
        bool unm = unmasked(j, r, ncr);
        bool lv = (j == NN) ? ncr : ((j == r) && !ncr);
        float rr = unm ? __expf(xv + vcw[c] - rm) * rsi : 0.f;
        float t = GAM * rr + (lv ? 0.2f : 0.f);
        if (t > 0.f) sImg += t * (__logf(t) - (lgt - rg));
        float r2 = unm ? __expf(xv + vtr - bm[c]) * bsi[c] : 0.f;
        float t2 = GAM * r2 + (lv ? 0.2f : 0.f);
        if (t2 > 0.f) sTxt += t2 * (__logf(t2) - (lgt - cg2[c]));
      }
    }
  }
  sImg = blockReduce256(sImg);
  sTxt = blockReduce256(sTxt);
  if (tid == 0) { imgP[rt * 33 + ct] = sImg; txtP[rt * 33 + ct] = sTxt; }
}

__global__ void finish_kernel(const float* imgP, const float* txtP,
                              const float* misc, float* out) {
  float vi = 0.f, vtx = 0.f;
  for (int idx = threadIdx.x; idx < 1056; idx += 256) { vi += imgP[idx]; vtx += txtP[idx]; }
  vi = blockReduce256(vi);
  vtx = blockReduce256(vtx);
  if (threadIdx.x == 0) {
    float loss_img = vi / 4096.0f;
    float loss_txt = vtx / 4097.0f;
    float loss_ul = 0.5f * (loss_img + loss_txt);
    float loss_op = misc[4] / 4096.0f;
    if (vi == 0.f && vtx == 0.f) loss_ul = 777.0f;
    if (!(loss_ul == loss_ul))   loss_ul = 888.0f;
    out[0] = loss_ul;
    out[1] = loss_op;
  }
}

extern "C" void kernel_launch(void* const* d_in, const int* in_sizes, int n_in,
                              void* d_out, int out_size, void* d_ws, size_t ws_size,
                              hipStream_t stream) {
  (void)in_sizes; (void)n_in; (void)out_size;
  const u16* img = (const u16*)d_in[0];
  const u16* txt = (const u16*)d_in[1];
  const u16* tno = (const u16*)d_in[2];
  const u16* ls  = (const u16*)d_in[3];
  float* out = (float*)d_out;

  ContrastiveLoss_83391085019222_kernel<<<1, 64, 0, stream>>>(out);

  size_t off = 0;
  char* w = (char*)d_ws;
  u16* S; u16* Abf; u16* Bbf;
  float *rsA0, *rsA1, *csA0, *csA1, *rsB0, *rsB1, *csB0, *csB1, *errs;
  float *rowLm, *rowLs, *rowGs, *colLm, *colLs, *colGs;
  float *vecs, *preds, *colvals, *gmin, *opP;
  float *LSMrow, *LBLm, *LBLs, *LSMcol, *LBTm, *LBTs, *imgP, *txtP, *misc;
  int* is_nc;
  #define ALLOC(ptr, type, nbytes) ptr = (type)(w + off); off = (off + (size_t)(nbytes) + 255) & ~(size_t)255
  ALLOC(S,      u16*,   (size_t)NN * LDA * 2);
  ALLOC(Abf,    u16*,   (size_t)NN * DD * 2);
  ALLOC(Bbf,    u16*,   (size_t)NN * DD * 2);
  ALLOC(rsA0,   float*, 4096 * 4);
  ALLOC(rsA1,   float*, 4096 * 4);
  ALLOC(csA0,   float*, 4104 * 4);
  ALLOC(csA1,   float*, 4104 * 4);
  ALLOC(rsB0,   float*, 4096 * 4);
  ALLOC(rsB1,   float*, 4096 * 4);
  ALLOC(csB0,   float*, 4104 * 4);
  ALLOC(csB1,   float*, 4104 * 4);
  ALLOC(errs,   float*, 256 * 4);
  ALLOC(rowLm,  float*, (size_t)33 * NN * 4);
  ALLOC(rowLs,  float*, (size_t)33 * NN * 4);
  ALLOC(rowGs,  float*, (size_t)33 * NN * 4);
  ALLOC(colLm,  float*, (size_t)32 * LDA * 4);
  ALLOC(colLs,  float*, (size_t)32 * LDA * 4);
  ALLOC(colGs,  float*, (size_t)32 * LDA * 4);
  ALLOC(vecs,   float*, 16400 * 4);
  ALLOC(preds,  float*, NN * 4);
  ALLOC(is_nc,  int*,   NN * 4);
  ALLOC(colvals,float*, NN * 4);
  ALLOC(gmin,   float*, 1024 * 4);
  ALLOC(opP,    float*, 1024 * 4);
  ALLOC(LSMrow, float*, NN * 4);
  ALLOC(LBLm,   float*, NN * 4);
  ALLOC(LBLs,   float*, NN * 4);
  ALLOC(LSMcol, float*, LDA * 4);
  ALLOC(LBTm,   float*, LDA * 4);
  ALLOC(LBTs,   float*, LDA * 4);
  ALLOC(imgP,   float*, 1056 * 4);
  ALLOC(txtP,   float*, 1056 * 4);
  ALLOC(misc,   float*, 64);
  #undef ALLOC

  if (ws_size < off) {
    diag_kernel<<<1, 64, 0, stream>>>(out, -(float)(ws_size / 1000000.0),
                                      -(float)(off / 1000000.0));
    return;
  }

  float* uvec  = vecs;
  float* vvec  = vecs + 4096;
  float* utvec = vecs + 8200;
  float* vtvec = vecs + 12304;
  float* errs1 = errs;
  float* errs2 = errs + 128;

  detect_kernel<<<1, 64, 0, stream>>>(img, misc);
  cvt_kernel<<<2048, 256, 0, stream>>>(img, txt, Abf, Bbf, misc);
  init_kernel<<<65, 256, 0, stream>>>(ls, vecs, errs, rsA0, csA0, misc);
  gemm_mfma<<<dim3(32, 32), 256, 0, stream>>>(Abf, Bbf, S, gmin);
  colvec_kernel<<<1024, 256, 0, stream>>>(img, txt, tno, S, colvals, opP, misc);
  reduce_kernel<<<1, 256, 0, stream>>>(gmin, colvals, opP, misc);

  preds_kernel<<<1024, 256, 0, stream>>>(S, misc, preds);
  rank_kernel<<<4096, 256, 0, stream>>>(preds, is_nc);

  /* persistent cooperative sinkhorn (one launch replaces 201) */
  {
    void* args[] = { (void*)&S, (void*)&misc, (void*)&errs1, (void*)&errs2,
                     (void*)&uvec, (void*)&utvec, (void*)&vvec, (void*)&vtvec,
                     (void*)&rsA0, (void*)&rsA1, (void*)&csA0, (void*)&csA1,
                     (void*)&rsB0, (void*)&rsB1, (void*)&csB0, (void*)&csB1,
                     (void*)&is_nc };
    (void)hipLaunchCooperativeKernel((const void*)sink_persist,
                                     dim3(SGRID), dim3(256), args, 0, stream);
  }

  final_pass<<<dim3(33, 32), 256, 0, stream>>>(S, vvec, vtvec, misc, is_nc,
                                               rowLm, rowLs, rowGs, colLm, colLs, colGs);
  final_combine<<<33, 256, 0, stream>>>(rowLm, rowLs, rowGs, colLm, colLs, colGs,
                                        LSMrow, LBLm, LBLs, LSMcol, LBTm, LBTs);
  loss_pass<<<dim3(33, 32), 256, 0, stream>>>(S, vvec, vtvec, misc, is_nc,
                                              LSMrow, LBLm, LBLs, LSMcol, LBTm, LBTs, imgP, txtP);
  finish_kernel<<<1, 256, 0, stream>>>(imgP, txtP, misc, out);
}
